// Round 1
// baseline (15484.811 us; speedup 1.0000x reference)
//
#include <hip/hip_runtime.h>
#include <math.h>

#define BT 256
#define LT 256
#define KT 128
#define HT 256
#define GB 64
#define BBk 4
#define NT 512

__device__ __forceinline__ float dot4(float4 w, float4 a, float acc){
  acc = fmaf(w.x, a.x, acc); acc = fmaf(w.y, a.y, acc);
  acc = fmaf(w.z, a.z, acc); acc = fmaf(w.w, a.w, acc);
  return acc;
}
__device__ __forceinline__ float sigf(float v){ return 1.0f/(1.0f+expf(-v)); }

// Pack src (J x D row-major) into dst[d4*J + j] = float4{src[j][4d4..4d4+3]}
__global__ void pack_w(const float* __restrict__ src, float4* __restrict__ dst,
                       int J, int D, int zero_diag, int total){
  int idx = blockIdx.x*blockDim.x + threadIdx.x;
  if (idx >= total) return;
  int j = idx % J, d4 = idx / J;
  int base = j*D + 4*d4;
  float4 v; v.x=src[base]; v.y=src[base+1]; v.z=src[base+2]; v.w=src[base+3];
  if (zero_diag){
    if (4*d4   == j) v.x = 0.0f;
    if (4*d4+1 == j) v.y = 0.0f;
    if (4*d4+2 == j) v.z = 0.0f;
    if (4*d4+3 == j) v.w = 0.0f;
  }
  dst[idx] = v;
}

__global__ void gxd_kernel(const float* __restrict__ W_gx, float* __restrict__ gxd){
  int k = threadIdx.x;
  if (k < KT) gxd[k] = W_gx[k*KT + k];
}

__global__ void msum_kernel(const float* __restrict__ mask, float* __restrict__ msum){
  __shared__ float red[256];
  int t = blockIdx.x;
  float acc = 0.0f;
  for (int i = threadIdx.x; i < BT*KT; i += 256){
    int b = i >> 7, k = i & 127;
    acc += mask[((size_t)b*LT + t)*KT + k];
  }
  red[threadIdx.x] = acc; __syncthreads();
  for (int s = 128; s > 0; s >>= 1){
    if (threadIdx.x < s) red[threadIdx.x] += red[threadIdx.x + s];
    __syncthreads();
  }
  if (threadIdx.x == 0) msum[t] = red[0];
}

struct __align__(16) SMem {
  float h[BBk][HT];        // carry h (h_prev)
  float hs[BBk][HT];       // h * gamma_h
  float axc[BBk][2*KT];    // act buffer: [gamma_x|mt] -> [x_c|mt] -> [c_c|mt]
  float de[BBk][KT];       // zeroed deltas (used in step)
  float dc[BBk][KT];       // raw delta carry
  float xt[BBk][KT];
  float mt[BBk][KT];
  float xh[BBk][KT];
  float zh[BBk][KT];
  float al[BBk][KT];
  float bgh[HT];
  float bih[3*HT];
  float bhh[3*HT];
  float bgx[KT]; float bhist[KT]; float bfeat[KT]; float bcomb[KT];
  float wout[HT]; float gxdl[KT];
  float predred[HT];
  float red[NT/64];
  int rn[BBk];
  float bout;
};

__global__ __launch_bounds__(NT) void rits_main(
    const float* __restrict__ x, const float* __restrict__ mask, const float* __restrict__ ts,
    const float* __restrict__ b_gh, const float* __restrict__ b_gx,
    const float* __restrict__ b_hist, const float* __restrict__ b_feat,
    const float* __restrict__ b_comb, const float* __restrict__ b_ih, const float* __restrict__ b_hh,
    const float* __restrict__ W_out, const float* __restrict__ b_out,
    const int* __restrict__ record_num,
    const float4* __restrict__ Pgh, const float4* __restrict__ Phist,
    const float4* __restrict__ Pfeat, const float4* __restrict__ Pcomb,
    const float4* __restrict__ Pih, const float4* __restrict__ Phh,
    const float* __restrict__ gxd, const float* __restrict__ msum,
    float* __restrict__ out)
{
  __shared__ SMem s;
  const int tid = threadIdx.x;
  const int b0 = blockIdx.x * BBk;

  for (int i = tid; i < BBk*HT; i += NT) (&s.h[0][0])[i] = 0.0f;
  for (int i = tid; i < HT; i += NT){ s.bgh[i] = b_gh[i]; s.wout[i] = W_out[i]; }
  for (int i = tid; i < 3*HT; i += NT){ s.bih[i] = b_ih[i]; s.bhh[i] = b_hh[i]; }
  if (tid < KT){
    s.bgx[tid] = b_gx[tid]; s.bhist[tid] = b_hist[tid];
    s.bfeat[tid] = b_feat[tid]; s.bcomb[tid] = b_comb[tid];
    s.gxdl[tid] = gxd[tid];
  }
  if (tid < BBk) s.rn[tid] = record_num[b0 + tid];
  if (tid == 0) s.bout = b_out[0];
  __syncthreads();

  float loss = 0.0f;
  const int eb = tid >> 7;        // (b,k) mapping for elementwise / J=128 matvecs
  const int ek = tid & 127;
  const int j256 = tid & 255;     // J=256 / J=768-grouped matvecs
  const int bh = tid >> 8;        // 0/1 -> batches {2bh, 2bh+1}
  const int bb0 = 2*bh, bb1 = 2*bh + 1;

  float gha[6];

  for (int t = 0; t < LT; ++t){
    // ---- Phase A: loads, delta update, gamma_x, act=[gx|mt] ----
    float inv;
    {
      float ms = msum[t];
      inv = 1.0f / (ms + 1e-5f);
      size_t xoff = ((size_t)(b0 + eb)*LT + t)*KT + ek;
      float xv = x[xoff], mv = mask[xoff];
      s.xt[eb][ek] = xv; s.mt[eb][ek] = mv;
      float dv;
      if (t == 0) dv = 1.0f;
      else {
        float tsc = ts[(size_t)(b0 + eb)*LT + t];
        float tsp = ts[(size_t)(b0 + eb)*LT + t - 1];
        dv = fabsf(tsc - tsp) + (1.0f - mv) * s.dc[eb][ek];
      }
      s.dc[eb][ek] = dv;
      float dev = (t < s.rn[eb]) ? dv : 0.0f;
      s.de[eb][ek] = dev;
      float gx = expf(-fmaxf(fmaf(dev, s.gxdl[ek], s.bgx[ek]), 0.0f));
      s.axc[eb][ek] = gx;
      s.axc[eb][KT + ek] = mv;
    }
    __syncthreads();

    // ---- Phase B: M1 gamma_h -> hs ; M4 alpha ----
    {
      const float4* a0 = (const float4*)s.de[bb0];
      const float4* a1 = (const float4*)s.de[bb1];
      float acc0 = 0.0f, acc1 = 0.0f;
      for (int k4 = 0; k4 < KT/4; ++k4){
        float4 w = Pgh[k4*HT + j256];
        float4 v0 = a0[k4], v1 = a1[k4];
        acc0 = dot4(w, v0, acc0); acc1 = dot4(w, v1, acc1);
      }
      float bb = s.bgh[j256];
      float g0 = expf(-fmaxf(acc0 + bb, 0.0f));
      float g1 = expf(-fmaxf(acc1 + bb, 0.0f));
      s.hs[bb0][j256] = s.h[bb0][j256] * g0;
      s.hs[bb1][j256] = s.h[bb1][j256] * g1;

      const float4* ax = (const float4*)s.axc[eb];
      float acc = 0.0f;
      for (int d4 = 0; d4 < 2*KT/4; ++d4){
        float4 w = Pcomb[d4*KT + ek];
        acc = dot4(w, ax[d4], acc);
      }
      s.al[eb][ek] = acc + s.bcomb[ek];
    }
    __syncthreads();

    // ---- Phase C: M2 x_h ; M6 gh (registers) ----
    {
      const float4* hsb = (const float4*)s.hs[eb];
      float acc = 0.0f;
      for (int d4 = 0; d4 < HT/4; ++d4){
        float4 w = Phist[d4*KT + ek];
        acc = dot4(w, hsb[d4], acc);
      }
      s.xh[eb][ek] = acc + s.bhist[ek];

      #pragma unroll
      for (int i = 0; i < 6; ++i) gha[i] = 0.0f;
      const float4* h0 = (const float4*)s.hs[bb0];
      const float4* h1 = (const float4*)s.hs[bb1];
      for (int d4 = 0; d4 < HT/4; ++d4){
        float4 w0 = Phh[d4*768 + j256];
        float4 w1 = Phh[d4*768 + 256 + j256];
        float4 w2 = Phh[d4*768 + 512 + j256];
        float4 v0 = h0[d4], v1 = h1[d4];
        gha[0] = dot4(w0, v0, gha[0]); gha[1] = dot4(w1, v0, gha[1]); gha[2] = dot4(w2, v0, gha[2]);
        gha[3] = dot4(w0, v1, gha[3]); gha[4] = dot4(w1, v1, gha[4]); gha[5] = dot4(w2, v1, gha[5]);
      }
    }
    __syncthreads();

    // ---- Phase D: x_c, loss S1 ----
    {
      float xv = s.xt[eb][ek], mv = s.mt[eb][ek], xhv = s.xh[eb][ek];
      loss += fabsf(xv - xhv) * mv * inv;
      s.axc[eb][ek] = mv*xv + (1.0f - mv)*xhv;
    }
    __syncthreads();

    // ---- Phase E: M3 z_h ----
    {
      const float4* ax = (const float4*)s.axc[eb];
      float acc = 0.0f;
      for (int k4 = 0; k4 < KT/4; ++k4){
        float4 w = Pfeat[k4*KT + ek];
        acc = dot4(w, ax[k4], acc);
      }
      s.zh[eb][ek] = acc + s.bfeat[ek];
    }
    __syncthreads();

    // ---- Phase F: c_h, c_c, losses S2/S3, imps write ----
    {
      float xv = s.xt[eb][ek], mv = s.mt[eb][ek], xhv = s.xh[eb][ek];
      float zv = s.zh[eb][ek], av = s.al[eb][ek];
      float e = (t < s.rn[eb]) ? 1.0f : 0.0f;
      float ch = av*zv + (1.0f - av)*xhv;
      loss += fabsf(xv - zv) * mv * e * inv;
      loss += fabsf(xv - ch) * mv * e * inv;
      float cc = mv*xv + (1.0f - mv)*ch;
      s.axc[eb][ek] = cc;
      out[((size_t)(b0 + eb)*LT + t)*KT + ek] = cc * e;
    }
    __syncthreads();

    // ---- Phase G: M5 gi (registers), gates, h update ----
    {
      float gia[6];
      #pragma unroll
      for (int i = 0; i < 6; ++i) gia[i] = 0.0f;
      const float4* a0 = (const float4*)s.axc[bb0];
      const float4* a1 = (const float4*)s.axc[bb1];
      for (int d4 = 0; d4 < 2*KT/4; ++d4){
        float4 w0 = Pih[d4*768 + j256];
        float4 w1 = Pih[d4*768 + 256 + j256];
        float4 w2 = Pih[d4*768 + 512 + j256];
        float4 v0 = a0[d4], v1 = a1[d4];
        gia[0] = dot4(w0, v0, gia[0]); gia[1] = dot4(w1, v0, gia[1]); gia[2] = dot4(w2, v0, gia[2]);
        gia[3] = dot4(w0, v1, gia[3]); gia[4] = dot4(w1, v1, gia[4]); gia[5] = dot4(w2, v1, gia[5]);
      }
      #pragma unroll
      for (int half = 0; half < 2; ++half){
        int b = 2*bh + half;
        float ir = gia[half*3+0] + s.bih[j256];
        float iz = gia[half*3+1] + s.bih[256 + j256];
        float ig = gia[half*3+2] + s.bih[512 + j256];
        float hr = gha[half*3+0] + s.bhh[j256];
        float hz = gha[half*3+1] + s.bhh[256 + j256];
        float hg = gha[half*3+2] + s.bhh[512 + j256];
        float r = sigf(ir + hr);
        float z = sigf(iz + hz);
        float n = tanhf(ig + r*hg);
        float hsv = s.hs[b][j256];
        float hn = (1.0f - z)*n + z*hsv;
        if (t < s.rn[b]) s.h[b][j256] = hn;
      }
    }
    __syncthreads();
  }

  // ---- loss reduction -> atomicAdd ----
  for (int off = 32; off; off >>= 1) loss += __shfl_down(loss, off);
  if ((tid & 63) == 0) s.red[tid >> 6] = loss;
  __syncthreads();
  if (tid == 0){
    float tot = 0.0f;
    for (int w = 0; w < NT/64; ++w) tot += s.red[w];
    atomicAdd(&out[(size_t)BT*LT*KT], tot);
  }

  // ---- predictions ----
  for (int b = 0; b < BBk; ++b){
    if (tid < HT) s.predred[tid] = s.h[b][tid] * s.wout[tid];
    __syncthreads();
    for (int st = HT/2; st > 0; st >>= 1){
      if (tid < st) s.predred[tid] += s.predred[tid + st];
      __syncthreads();
    }
    if (tid == 0){
      float v = s.predred[0] + s.bout;
      out[(size_t)BT*LT*KT + 1 + b0 + b] = 1.0f/(1.0f + expf(-v));
    }
    __syncthreads();
  }
}

extern "C" void kernel_launch(void* const* d_in, const int* in_sizes, int n_in,
                              void* d_out, int out_size, void* d_ws, size_t ws_size,
                              hipStream_t stream){
  const float* x      = (const float*)d_in[0];
  const float* mask   = (const float*)d_in[1];
  const float* ts     = (const float*)d_in[2];
  const float* W_gh   = (const float*)d_in[3];
  const float* b_gh   = (const float*)d_in[4];
  const float* W_gx   = (const float*)d_in[5];
  const float* b_gx   = (const float*)d_in[6];
  const float* W_hist = (const float*)d_in[7];
  const float* b_hist = (const float*)d_in[8];
  const float* W_feat = (const float*)d_in[9];
  const float* b_feat = (const float*)d_in[10];
  const float* W_comb = (const float*)d_in[11];
  const float* b_comb = (const float*)d_in[12];
  const float* W_ih   = (const float*)d_in[13];
  const float* W_hh   = (const float*)d_in[14];
  const float* b_ih   = (const float*)d_in[15];
  const float* b_hh   = (const float*)d_in[16];
  const float* W_out  = (const float*)d_in[17];
  const float* b_out  = (const float*)d_in[18];
  const int*   rn     = (const int*)d_in[19];
  float* out = (float*)d_out;
  float* ws  = (float*)d_ws;

  float4* Pgh   = (float4*)(ws + 0);        // 32768 floats
  float4* Phist = (float4*)(ws + 32768);    // 32768
  float4* Pfeat = (float4*)(ws + 65536);    // 16384
  float4* Pcomb = (float4*)(ws + 81920);    // 32768
  float4* Pih   = (float4*)(ws + 114688);   // 196608
  float4* Phh   = (float4*)(ws + 311296);   // 196608
  float*  gxd   = ws + 507904;              // 128
  float*  msum  = ws + 508032;              // 256

  auto pk = [&](const float* src, float4* dst, int J, int D, int zd){
    int total = J*D/4;
    pack_w<<<dim3((total + 255)/256), dim3(256), 0, stream>>>(src, dst, J, D, zd, total);
  };
  pk(W_gh,   Pgh,   256, 128, 0);
  pk(W_hist, Phist, 128, 256, 0);
  pk(W_feat, Pfeat, 128, 128, 1);
  pk(W_comb, Pcomb, 128, 256, 0);
  pk(W_ih,   Pih,   768, 256, 0);
  pk(W_hh,   Phh,   768, 256, 0);
  gxd_kernel<<<dim3(1), dim3(128), 0, stream>>>(W_gx, gxd);
  msum_kernel<<<dim3(LT), dim3(256), 0, stream>>>(mask, msum);
  hipMemsetAsync((void*)(out + (size_t)BT*LT*KT), 0, sizeof(float), stream);
  rits_main<<<dim3(GB), dim3(NT), 0, stream>>>(x, mask, ts,
      b_gh, b_gx, b_hist, b_feat, b_comb, b_ih, b_hh, W_out, b_out, rn,
      (const float4*)Pgh, (const float4*)Phist, (const float4*)Pfeat,
      (const float4*)Pcomb, (const float4*)Pih, (const float4*)Phh,
      gxd, msum, out);
}

// Round 2
// 4192.655 us; speedup vs baseline: 3.6933x; 3.6933x over previous
//
#include <hip/hip_runtime.h>
#include <math.h>

#define BT 256
#define LT 256
#define KT 128
#define HT 256
#define GB 64
#define NT 1024
#define LOSS_IDX ((size_t)BT*LT*KT)

typedef _Float16 h2 __attribute__((ext_vector_type(2)));
typedef _Float16 h8 __attribute__((ext_vector_type(8)));

#if defined(__has_builtin)
#if __has_builtin(__builtin_amdgcn_fdot2)
#define HAVE_FDOT2 1
#endif
#endif

__device__ __forceinline__ float fd2(h2 a, h2 b, float c){
#ifdef HAVE_FDOT2
  return __builtin_amdgcn_fdot2(a, b, c, false);
#else
  return c + (float)a[0]*(float)b[0] + (float)a[1]*(float)b[1];
#endif
}

__device__ __forceinline__ float dot8(h8 w, h8 a, float acc){
  acc = fd2(__builtin_shufflevector(w,w,0,1), __builtin_shufflevector(a,a,0,1), acc);
  acc = fd2(__builtin_shufflevector(w,w,2,3), __builtin_shufflevector(a,a,2,3), acc);
  acc = fd2(__builtin_shufflevector(w,w,4,5), __builtin_shufflevector(a,a,4,5), acc);
  acc = fd2(__builtin_shufflevector(w,w,6,7), __builtin_shufflevector(a,a,6,7), acc);
  return acc;
}

__device__ __forceinline__ float sel4(float a0, float a1, float a2, float a3, int q){
  float x01 = (q & 1) ? a1 : a0;
  float x23 = (q & 1) ? a3 : a2;
  return (q & 2) ? x23 : x01;
}

__device__ __forceinline__ float sigf(float v){ return 1.0f/(1.0f + __expf(-v)); }
__device__ __forceinline__ float tanh_fast(float v){
  float a = fminf(fabsf(v), 15.0f);
  float e2 = __expf(2.0f*a);
  float r = (e2 - 1.0f)/(e2 + 1.0f);
  return copysignf(r, v);
}

// ---- pack: src (Jtot x D row-major fp32) -> f16 tiles matching lane layout ----
// idx -> lane(q*16+jlo), i (uint4 within chunk), r (row group), tile (j-group of 16)
__global__ void pack_f16(const float* __restrict__ src, _Float16* __restrict__ dst,
                         int U, int R, int D, int zero_diag, int total_h8){
  int idx = blockIdx.x*256 + threadIdx.x;
  if (idx >= total_h8) return;
  int lane = idx & 63, jlo = lane & 15, q = lane >> 4;
  int I = D >> 5;
  int rest = idx >> 6;
  int i = rest % I; rest /= I;
  int r = rest % R; int tile = rest / R;
  int u = tile*16 + jlo;
  int j = r*U + u;
  int col0 = q*(D >> 2) + i*8;
  #pragma unroll
  for (int e = 0; e < 8; ++e){
    float v = src[(size_t)j*D + col0 + e];
    if (zero_diag && (col0 + e) == u) v = 0.0f;
    dst[(size_t)idx*8 + e] = (_Float16)v;
  }
}

__global__ void gxd_kernel(const float* __restrict__ W_gx, float* __restrict__ gxd){
  int k = threadIdx.x;
  if (k < KT) gxd[k] = W_gx[k*KT + k];
}

__global__ void msum_kernel(const float* __restrict__ mask, float* __restrict__ msumInv){
  __shared__ float red[256];
  int t = blockIdx.x;
  float acc = 0.0f;
  for (int i = threadIdx.x; i < BT*KT; i += 256){
    int b = i >> 7, k = i & 127;
    acc += mask[((size_t)b*LT + t)*KT + k];
  }
  red[threadIdx.x] = acc; __syncthreads();
  for (int s = 128; s > 0; s >>= 1){
    if (threadIdx.x < s) red[threadIdx.x] += red[threadIdx.x + s];
    __syncthreads();
  }
  if (threadIdx.x == 0) msumInv[t] = 1.0f/(red[0] + 1e-5f);
}

struct __align__(16) SMem {
  float h[4][260];      // padded stride 260: kills 4-way bank conflict on (q,u) access
  float hs32[4][260];
  float xt[4][132];
  float mt[4][132];
  float xh32[4][132];
  float al32[4][132];
  float bgh[HT];
  float bih[3*HT];
  float bhh[3*HT];
  float bgx[KT]; float bhist[KT]; float bfeat[KT]; float bcomb[KT]; float gxdl[KT];
  float wout[HT];
  float red[16];
  alignas(16) _Float16 deh[4][KT];
  alignas(16) _Float16 axch[4][2*KT];   // [gamma_x | m]
  alignas(16) _Float16 hsh[4][HT];
  alignas(16) _Float16 xch[4][KT];
  alignas(16) _Float16 cch[4][2*KT];    // [c_c | m]
  int rn[4];
  float bout;
};

__global__ __launch_bounds__(NT, 4) void rits_main(
    const float* __restrict__ x, const float* __restrict__ mask, const float* __restrict__ ts,
    const float* __restrict__ b_gh, const float* __restrict__ b_gx,
    const float* __restrict__ b_hist, const float* __restrict__ b_feat,
    const float* __restrict__ b_comb, const float* __restrict__ b_ih, const float* __restrict__ b_hh,
    const float* __restrict__ W_out, const float* __restrict__ b_out,
    const int* __restrict__ record_num,
    const h8* __restrict__ Pgh, const h8* __restrict__ Phist,
    const h8* __restrict__ Pfeat, const h8* __restrict__ Pcomb,
    const h8* __restrict__ Pih, const h8* __restrict__ Phh,
    const float* __restrict__ gxd, const float* __restrict__ msumInv,
    float* __restrict__ out)
{
  __shared__ SMem s;
  const int tid = threadIdx.x;
  const int lane = tid & 63;
  const int wv = tid >> 6;
  const int jlo = lane & 15;
  const int q = lane >> 4;
  const int b0 = blockIdx.x * 4;

  for (int i = tid; i < 4*260; i += NT) (&s.h[0][0])[i] = 0.0f;
  for (int i = tid; i < HT; i += NT){ s.bgh[i] = b_gh[i]; s.wout[i] = W_out[i]; }
  for (int i = tid; i < 3*HT; i += NT){ s.bih[i] = b_ih[i]; s.bhh[i] = b_hh[i]; }
  if (tid < KT){
    s.bgx[tid] = b_gx[tid]; s.bhist[tid] = b_hist[tid];
    s.bfeat[tid] = b_feat[tid]; s.bcomb[tid] = b_comb[tid];
    s.gxdl[tid] = gxd[tid];
  }
  if (tid < 4) s.rn[tid] = record_num[b0 + tid];
  if (tid == 0) s.bout = b_out[0];
  __syncthreads();

  // A-phase thread-persistent state
  const int eb = tid >> 7, ek = tid & 127;
  float dcr = 1.0f;
  float tprev = 0.0f;
  if (tid < 512) tprev = ts[(size_t)(b0 + eb)*LT];

  float loss = 0.0f;
  float gha0 = 0.0f, gha1 = 0.0f, gha2 = 0.0f;

  for (int t = 0; t < LT; ++t){
    const float inv = msumInv[t];

    // ---- A: elementwise (tid<512): delta, gamma_x, stage x/m ----
    if (tid < 512){
      size_t xoff = ((size_t)(b0 + eb)*LT + t)*KT + ek;
      float xv = x[xoff], mv = mask[xoff];
      s.xt[eb][ek] = xv; s.mt[eb][ek] = mv;
      float dv;
      if (t == 0){ dv = 1.0f; }
      else {
        float tsc = ts[(size_t)(b0 + eb)*LT + t];
        dv = fabsf(tsc - tprev) + (1.0f - mv)*dcr;
        tprev = tsc;
      }
      dcr = dv;
      float e = (t < s.rn[eb]) ? 1.0f : 0.0f;
      float dev = dv * e;
      s.deh[eb][ek] = (_Float16)dev;
      float gx = __expf(-fmaxf(fmaf(dev, s.gxdl[ek], s.bgx[ek]), 0.0f));
      s.axch[eb][ek] = (_Float16)gx;
      s.axch[eb][KT + ek] = (_Float16)mv;
      s.cch[eb][KT + ek] = (_Float16)mv;
    }
    __syncthreads();

    // ---- B: M1 gamma_h -> hs (J=256, D=128) ----
    {
      float a4[4] = {0,0,0,0};
      #pragma unroll
      for (int i = 0; i < 4; ++i){
        h8 w = Pgh[(wv*4 + i)*64 + lane];
        #pragma unroll
        for (int b = 0; b < 4; ++b){
          h8 av = *(const h8*)&s.deh[b][q*32 + i*8];
          a4[b] = dot8(w, av, a4[b]);
        }
      }
      #pragma unroll
      for (int k = 0; k < 4; ++k){
        a4[k] += __shfl_xor(a4[k], 16);
        a4[k] += __shfl_xor(a4[k], 32);
      }
      float acc = sel4(a4[0], a4[1], a4[2], a4[3], q);
      int j = wv*16 + jlo;
      float g = __expf(-fmaxf(acc + s.bgh[j], 0.0f));
      float hsv = s.h[q][j] * g;
      s.hs32[q][j] = hsv;
      s.hsh[q][j] = (_Float16)hsv;
    }
    __syncthreads();

    // ---- C: M6 gh (all waves) + M2 x_h (wv<8) / M4 alpha (wv>=8) ----
    {
      float a12[12];
      #pragma unroll
      for (int k = 0; k < 12; ++k) a12[k] = 0.0f;
      #pragma unroll 2
      for (int i = 0; i < 8; ++i){
        h8 w0 = Phh[((wv*3 + 0)*8 + i)*64 + lane];
        h8 w1 = Phh[((wv*3 + 1)*8 + i)*64 + lane];
        h8 w2 = Phh[((wv*3 + 2)*8 + i)*64 + lane];
        #pragma unroll
        for (int b = 0; b < 4; ++b){
          h8 av = *(const h8*)&s.hsh[b][q*64 + i*8];
          a12[b]     = dot8(w0, av, a12[b]);
          a12[4 + b] = dot8(w1, av, a12[4 + b]);
          a12[8 + b] = dot8(w2, av, a12[8 + b]);
        }
      }
      #pragma unroll
      for (int k = 0; k < 12; ++k){
        a12[k] += __shfl_xor(a12[k], 16);
        a12[k] += __shfl_xor(a12[k], 32);
      }
      gha0 = sel4(a12[0], a12[1], a12[2], a12[3], q);
      gha1 = sel4(a12[4], a12[5], a12[6], a12[7], q);
      gha2 = sel4(a12[8], a12[9], a12[10], a12[11], q);

      float c4[4] = {0,0,0,0};
      if (wv < 8){
        #pragma unroll
        for (int i = 0; i < 8; ++i){
          h8 w = Phist[(wv*8 + i)*64 + lane];
          #pragma unroll
          for (int b = 0; b < 4; ++b){
            h8 av = *(const h8*)&s.hsh[b][q*64 + i*8];
            c4[b] = dot8(w, av, c4[b]);
          }
        }
        #pragma unroll
        for (int k = 0; k < 4; ++k){
          c4[k] += __shfl_xor(c4[k], 16);
          c4[k] += __shfl_xor(c4[k], 32);
        }
        int j = wv*16 + jlo;
        float xhv = sel4(c4[0], c4[1], c4[2], c4[3], q) + s.bhist[j];
        float xv = s.xt[q][j], mv = s.mt[q][j];
        loss += fabsf(xv - xhv) * mv * inv;
        float xcv = mv*xv + (1.0f - mv)*xhv;
        s.xh32[q][j] = xhv;
        s.xch[q][j] = (_Float16)xcv;
      } else {
        #pragma unroll
        for (int i = 0; i < 8; ++i){
          h8 w = Pcomb[((wv - 8)*8 + i)*64 + lane];
          #pragma unroll
          for (int b = 0; b < 4; ++b){
            h8 av = *(const h8*)&s.axch[b][q*64 + i*8];
            c4[b] = dot8(w, av, c4[b]);
          }
        }
        #pragma unroll
        for (int k = 0; k < 4; ++k){
          c4[k] += __shfl_xor(c4[k], 16);
          c4[k] += __shfl_xor(c4[k], 32);
        }
        int j = (wv - 8)*16 + jlo;
        s.al32[q][j] = sel4(c4[0], c4[1], c4[2], c4[3], q) + s.bcomb[j];
      }
    }
    __syncthreads();

    // ---- E: M3 z_h (wv<8, J=128, D=128) + epilogue: c_h, c_c, losses, out ----
    if (wv < 8){
      float c4[4] = {0,0,0,0};
      #pragma unroll
      for (int i = 0; i < 4; ++i){
        h8 w = Pfeat[(wv*4 + i)*64 + lane];
        #pragma unroll
        for (int b = 0; b < 4; ++b){
          h8 av = *(const h8*)&s.xch[b][q*32 + i*8];
          c4[b] = dot8(w, av, c4[b]);
        }
      }
      #pragma unroll
      for (int k = 0; k < 4; ++k){
        c4[k] += __shfl_xor(c4[k], 16);
        c4[k] += __shfl_xor(c4[k], 32);
      }
      int j = wv*16 + jlo;
      float zhv = sel4(c4[0], c4[1], c4[2], c4[3], q) + s.bfeat[j];
      float xv = s.xt[q][j], mv = s.mt[q][j];
      float xhv = s.xh32[q][j], alv = s.al32[q][j];
      float e = (t < s.rn[q]) ? 1.0f : 0.0f;
      float chv = alv*zhv + (1.0f - alv)*xhv;
      loss += fabsf(xv - zhv) * mv * e * inv;
      loss += fabsf(xv - chv) * mv * e * inv;
      float ccv = mv*xv + (1.0f - mv)*chv;
      out[((size_t)(b0 + q)*LT + t)*KT + j] = ccv * e;
      s.cch[q][j] = (_Float16)ccv;
    }
    __syncthreads();

    // ---- G: M5 gi (all waves) + gates + h update ----
    {
      float a12[12];
      #pragma unroll
      for (int k = 0; k < 12; ++k) a12[k] = 0.0f;
      #pragma unroll 2
      for (int i = 0; i < 8; ++i){
        h8 w0 = Pih[((wv*3 + 0)*8 + i)*64 + lane];
        h8 w1 = Pih[((wv*3 + 1)*8 + i)*64 + lane];
        h8 w2 = Pih[((wv*3 + 2)*8 + i)*64 + lane];
        #pragma unroll
        for (int b = 0; b < 4; ++b){
          h8 av = *(const h8*)&s.cch[b][q*64 + i*8];
          a12[b]     = dot8(w0, av, a12[b]);
          a12[4 + b] = dot8(w1, av, a12[4 + b]);
          a12[8 + b] = dot8(w2, av, a12[8 + b]);
        }
      }
      #pragma unroll
      for (int k = 0; k < 12; ++k){
        a12[k] += __shfl_xor(a12[k], 16);
        a12[k] += __shfl_xor(a12[k], 32);
      }
      int u = wv*16 + jlo;
      float ir = sel4(a12[0], a12[1], a12[2], a12[3], q) + s.bih[u];
      float iz = sel4(a12[4], a12[5], a12[6], a12[7], q) + s.bih[HT + u];
      float ig = sel4(a12[8], a12[9], a12[10], a12[11], q) + s.bih[2*HT + u];
      float hr = gha0 + s.bhh[u];
      float hz = gha1 + s.bhh[HT + u];
      float hg = gha2 + s.bhh[2*HT + u];
      float r = sigf(ir + hr);
      float z = sigf(iz + hz);
      float n = tanh_fast(ig + r*hg);
      float hsv = s.hs32[q][u];
      float hn = (1.0f - z)*n + z*hsv;
      if (t < s.rn[q]) s.h[q][u] = hn;
    }
    __syncthreads();
  }

  // ---- loss reduction ----
  #pragma unroll
  for (int off = 32; off; off >>= 1) loss += __shfl_down(loss, off);
  if (lane == 0) s.red[wv] = loss;
  __syncthreads();
  if (tid == 0){
    float tot = 0.0f;
    #pragma unroll
    for (int w = 0; w < 16; ++w) tot += s.red[w];
    atomicAdd(&out[LOSS_IDX], tot);
  }

  // ---- predictions ----
  if (wv < 4){
    int b = wv;
    float acc = 0.0f;
    #pragma unroll
    for (int u = 0; u < HT; u += 64) acc += s.h[b][u + lane] * s.wout[u + lane];
    #pragma unroll
    for (int off = 32; off; off >>= 1) acc += __shfl_xor(acc, off);
    if (lane == 0) out[LOSS_IDX + 1 + b0 + b] = sigf(acc + s.bout);
  }
}

extern "C" void kernel_launch(void* const* d_in, const int* in_sizes, int n_in,
                              void* d_out, int out_size, void* d_ws, size_t ws_size,
                              hipStream_t stream){
  const float* x      = (const float*)d_in[0];
  const float* mask   = (const float*)d_in[1];
  const float* ts     = (const float*)d_in[2];
  const float* W_gh   = (const float*)d_in[3];
  const float* b_gh   = (const float*)d_in[4];
  const float* W_gx   = (const float*)d_in[5];
  const float* b_gx   = (const float*)d_in[6];
  const float* W_hist = (const float*)d_in[7];
  const float* b_hist = (const float*)d_in[8];
  const float* W_feat = (const float*)d_in[9];
  const float* b_feat = (const float*)d_in[10];
  const float* W_comb = (const float*)d_in[11];
  const float* b_comb = (const float*)d_in[12];
  const float* W_ih   = (const float*)d_in[13];
  const float* W_hh   = (const float*)d_in[14];
  const float* b_ih   = (const float*)d_in[15];
  const float* b_hh   = (const float*)d_in[16];
  const float* W_out  = (const float*)d_in[17];
  const float* b_out  = (const float*)d_in[18];
  const int*   rn     = (const int*)d_in[19];
  float* out = (float*)d_out;
  char* ws = (char*)d_ws;

  // byte offsets into workspace (all 16B aligned)
  _Float16* Pgh   = (_Float16*)(ws + 0);        //  64 KB (4096 h8)
  _Float16* Phist = (_Float16*)(ws + 65536);    //  64 KB
  _Float16* Pfeat = (_Float16*)(ws + 131072);   //  32 KB
  _Float16* Pcomb = (_Float16*)(ws + 163840);   //  64 KB
  _Float16* Pih   = (_Float16*)(ws + 229376);   // 384 KB
  _Float16* Phh   = (_Float16*)(ws + 622592);   // 384 KB
  float* msumInv  = (float*)(ws + 1015808);     // 1 KB
  float* gxd      = (float*)(ws + 1016832);     // 0.5 KB

  auto pk = [&](const float* src, _Float16* dst, int U, int R, int D, int zd){
    int total = U*R*D/8;
    pack_f16<<<dim3((total + 255)/256), dim3(256), 0, stream>>>(src, dst, U, R, D, zd, total);
  };
  pk(W_gh,   Pgh,   256, 1, 128, 0);
  pk(W_hist, Phist, 128, 1, 256, 0);
  pk(W_feat, Pfeat, 128, 1, 128, 1);
  pk(W_comb, Pcomb, 128, 1, 256, 0);
  pk(W_ih,   Pih,   256, 3, 256, 0);
  pk(W_hh,   Phh,   256, 3, 256, 0);
  gxd_kernel<<<dim3(1), dim3(128), 0, stream>>>(W_gx, gxd);
  msum_kernel<<<dim3(LT), dim3(256), 0, stream>>>(mask, msumInv);
  hipMemsetAsync((void*)(out + LOSS_IDX), 0, sizeof(float), stream);

  rits_main<<<dim3(GB), dim3(NT), 0, stream>>>(x, mask, ts,
      b_gh, b_gx, b_hist, b_feat, b_comb, b_ih, b_hh, W_out, b_out, rn,
      (const h8*)Pgh, (const h8*)Phist, (const h8*)Pfeat,
      (const h8*)Pcomb, (const h8*)Pih, (const h8*)Phh,
      gxd, msumInv, out);
}